// Round 24
// baseline (200.673 us; speedup 1.0000x reference)
//
#include <hip/hip_runtime.h>
#include <math.h>

#define NN 50000
#define NE 800000
#define FD 128
#define CIN 256
#define NCLS 16
#define SCAN_B 196   // ceil(NN/256)
#define NCOPY 32
#define RB 1024      // reorder blocks (fixed: edge->copy map depends on it)
#define RSTRIDE (RB * 256)

typedef short s16x8 __attribute__((ext_vector_type(8)));
typedef float f32x4 __attribute__((ext_vector_type(4)));
typedef float f32x2 __attribute__((ext_vector_type(2)));

__device__ __forceinline__ unsigned short f2bf(float f) {
  union { float f; unsigned u; } v; v.f = f;
  unsigned r = v.u + 0x7fffu + ((v.u >> 16) & 1u);
  return (unsigned short)(r >> 16);
}

__device__ __forceinline__ float bf2f(unsigned short h) {
  union { unsigned u; float f; } v; v.u = ((unsigned)h) << 16;
  return v.f;
}

// fast transcendentals: v_exp_f32 computes 2^x; rcp is 1-instr approx
__device__ __forceinline__ float fast_sigmoid(float x) {
  return __builtin_amdgcn_rcpf(1.0f + exp2f(-1.44269504f * x));
}
__device__ __forceinline__ float fast_tanh(float x) {
  return 1.0f - 2.0f * __builtin_amdgcn_rcpf(1.0f + exp2f(2.88539008f * x));
}

// fp8 (OCP e4m3) helpers: HW single-instruction converts on gfx950
__device__ __forceinline__ unsigned char f2fp8(float v) {
  int pk = __builtin_amdgcn_cvt_pk_fp8_f32(v, 0.f, 0, false);
  return (unsigned char)(pk & 0xff);
}
__device__ __forceinline__ void fp8_set4(float* a, int v) {
  f32x2 lo = __builtin_amdgcn_cvt_pk_f32_fp8(v, false);
  f32x2 hi = __builtin_amdgcn_cvt_pk_f32_fp8(v, true);
  a[0] = lo.x; a[1] = lo.y; a[2] = hi.x; a[3] = hi.y;
}
__device__ __forceinline__ void fp8_fma4(float* a, int v, float wv) {
  f32x2 lo = __builtin_amdgcn_cvt_pk_f32_fp8(v, false);
  f32x2 hi = __builtin_amdgcn_cvt_pk_f32_fp8(v, true);
  a[0] = fmaf(wv, lo.x, a[0]); a[1] = fmaf(wv, lo.y, a[1]);
  a[2] = fmaf(wv, hi.x, a[2]); a[3] = fmaf(wv, hi.y, a[3]);
}

// -- fused prep + histogram: weight transpose/bias fold hides under atomics --
// parts must be pre-zeroed (hipMemsetAsync). Edge->copy mapping (c =
// blockIdx&31, grid-stride RSTRIDE) MUST match k_reorder_xw's reorder path.

__global__ void k_prep_hist(
    const float* __restrict__ Wz0, const float* __restrict__ Wz1,
    const float* __restrict__ Wr0, const float* __restrict__ Wr1,
    const float* __restrict__ Wh0, const float* __restrict__ Wh1,
    const float* __restrict__ Wg, const float* __restrict__ Wl,
    const float* __restrict__ bg, const float* __restrict__ bz,
    const float* __restrict__ br, const float* __restrict__ bh,
    const int* __restrict__ dst, const float* __restrict__ ew,
    short* __restrict__ wtzr, short* __restrict__ wth,
    short* __restrict__ wtg, short* __restrict__ wtl,
    float* __restrict__ bzp, float* __restrict__ brp,
    float* __restrict__ bhp, unsigned long long* __restrict__ parts) {
  int i = blockIdx.x * blockDim.x + threadIdx.x;
  if (i < 65536) {
    int n = i >> 8, k = i & 255;
    float v = (n < 128) ? (Wz0[k * 128 + n] + Wz1[k * 128 + n])
                        : (Wr0[k * 128 + (n - 128)] + Wr1[k * 128 + (n - 128)]);
    wtzr[i] = (short)f2bf(v);
  } else if (i < 98304) {
    int j = i - 65536; int n = j >> 8, k = j & 255;
    wth[j] = (short)f2bf(Wh0[k * 128 + n] + Wh1[k * 128 + n]);
  } else if (i < 114688) {
    int j = i - 98304; int n = j >> 7, k = j & 127;
    wtg[j] = (short)f2bf(Wg[k * 128 + n]);
  } else if (i < 116736) {
    int j = i - 114688; int n = j >> 7, k = j & 127;
    wtl[j] = (short)f2bf(Wl[k * 16 + n]);
  } else if (i < 116864) {
    int c = i - 116736;
    float sz = bz[c], sr = br[c], sh = bh[c];
    for (int k = 0; k < 128; ++k) {
      float gv = bg[k];
      sz += gv * (Wz0[k * 128 + c] + Wz1[k * 128 + c]);
      sr += gv * (Wr0[k * 128 + c] + Wr1[k * 128 + c]);
      sh += gv * (Wh0[k * 128 + c] + Wh1[k * 128 + c]);
    }
    bzp[c] = sz; brp[c] = sr; bhp[c] = sh;
  }
  // histogram (all threads)
  const int c = blockIdx.x & (NCOPY - 1);
  unsigned long long* __restrict__ p = parts + (size_t)c * NN;
  for (int e = i; e < NE; e += RSTRIDE) {
    int d = dst[e];
    unsigned long long pk = (1ULL << 40) +
        (unsigned long long)(ew[e] * 4294967296.0f + 0.5f);
    atomicAdd(&p[d], pk);
  }
}

// fused: fold copies -> dinv ; block-local exclusive scan of counts
__global__ __launch_bounds__(256) void k_reduce_scan1(
    const unsigned long long* __restrict__ parts, float* __restrict__ dinv,
    int* __restrict__ base, int* __restrict__ bsum) {
  __shared__ int ts[256];
  const int t = threadIdx.x, b = blockIdx.x;
  const int i = b * 256 + t;
  int ct = 0;
  if (i < NN) {
    double frac = 0.0;
#pragma unroll
    for (int c = 0; c < NCOPY; ++c) {
      unsigned long long v = parts[(size_t)c * NN + i];
      ct += (int)(v >> 40);
      frac += (double)(v & 0xFFFFFFFFFFULL);
    }
    double deg = 1.0 + frac * (1.0 / 4294967296.0);
    dinv[i] = rsqrtf((float)deg);
  }
  ts[t] = ct;
  __syncthreads();
#pragma unroll
  for (int off = 1; off < 256; off <<= 1) {
    int u = (t >= off) ? ts[t - off] : 0;
    __syncthreads();
    ts[t] += u;
    __syncthreads();
  }
  if (i < NN) base[i] = ts[t] - ct;
  if (t == 255) bsum[b] = ts[255];
}

// scan2 folded in: every block redundantly scans bsum[196] in LDS,
// picks its own offset, finalizes base and carves per-copy cursors.
__global__ __launch_bounds__(256) void k_scan23(
    int* __restrict__ base, const int* __restrict__ bsum,
    const unsigned long long* __restrict__ parts, int* __restrict__ off16) {
  __shared__ int ts[256];
  __shared__ int bo;
  const int t = threadIdx.x;
  int v = (t < SCAN_B) ? bsum[t] : 0;
  ts[t] = v;
  __syncthreads();
#pragma unroll
  for (int off = 1; off < 256; off <<= 1) {
    int u = (t >= off) ? ts[t - off] : 0;
    __syncthreads();
    ts[t] += u;
    __syncthreads();
  }
  if (t == blockIdx.x) bo = ts[t] - v;          // boff[blockIdx]
  if (blockIdx.x == 0 && t == 255) base[NN] = ts[255];
  __syncthreads();
  const int boff = bo;
  const int i = blockIdx.x * 256 + t;
  if (i >= NN) return;
  int b = base[i] + boff;
  base[i] = b;
  int run = b;
#pragma unroll
  for (int c = 0; c < NCOPY; ++c) {
    off16[(size_t)c * NN + i] = run;
    run += (int)(parts[(size_t)c * NN + i] >> 40);
  }
}

// ---- heterogeneous fused kernel: reorder (blocks 0..RB-1)  ||  xw GEMM ----
// Reorder path: stride RSTRIDE, c = blockIdx&31 — MUST match k_prep_hist.
// xw path: blocks RB.. compute xws8 = fp8(dinv[n] * (x @ Wg)) via MFMA.

__global__ __launch_bounds__(256) void k_reorder_xw(
    const int* __restrict__ ei, const float* __restrict__ ew,
    int* __restrict__ off16, int2* __restrict__ edge_s,
    const float* __restrict__ x, const short* __restrict__ wtg,
    const float* __restrict__ dinv, unsigned char* __restrict__ xws8) {
  if (blockIdx.x < RB) {
    // ---------------- reorder path ----------------
    const int c = blockIdx.x & (NCOPY - 1);
    int* __restrict__ cur = off16 + (size_t)c * NN;
    int i = blockIdx.x * 256 + threadIdx.x;
    const int* __restrict__ src = ei;
    const int* __restrict__ dst = ei + NE;
    for (int e = i; e < NE; e += RSTRIDE) {
      int s = src[e], d = dst[e];
      int pos = atomicAdd(&cur[d], 1);
      edge_s[pos] = make_int2(s, __float_as_int(ew[e]));
    }
    return;
  }
  // ---------------- xw MFMA path ----------------
  __shared__ __align__(16) short As[64][40];
  const int tid = threadIdx.x;
  const int w = tid >> 6, l = tid & 63, g = l >> 4, ln = l & 15;
  const int n0 = (blockIdx.x - RB) * 64;
  const int srow = tid >> 2, sk0 = (tid & 3) << 3;
  const s16x8* wt8 = (const s16x8*)wtg;

  f32x4 acc[4][2];
#pragma unroll
  for (int mi = 0; mi < 4; ++mi)
#pragma unroll
    for (int ni = 0; ni < 2; ++ni) acc[mi][ni] = (f32x4){0.f, 0.f, 0.f, 0.f};

  for (int kci = 0; kci < 4; ++kci) {
    int kg = kci * 32 + sk0;
    int n = n0 + srow;
    s16x8 av = {0, 0, 0, 0, 0, 0, 0, 0};
    if (n < NN) {
      const float* src = x + (size_t)n * FD + kg;
      float4 f0 = *(const float4*)src;
      float4 f1 = *(const float4*)(src + 4);
      av[0] = (short)f2bf(f0.x); av[1] = (short)f2bf(f0.y);
      av[2] = (short)f2bf(f0.z); av[3] = (short)f2bf(f0.w);
      av[4] = (short)f2bf(f1.x); av[5] = (short)f2bf(f1.y);
      av[6] = (short)f2bf(f1.z); av[7] = (short)f2bf(f1.w);
    }
    __syncthreads();
    *(s16x8*)&As[srow][sk0] = av;
    __syncthreads();
    s16x8 b[2], a[4];
#pragma unroll
    for (int ni = 0; ni < 2; ++ni) {
      int col = w * 32 + ni * 16 + ln;
      b[ni] = wt8[(size_t)col * 16 + kci * 4 + g];
    }
#pragma unroll
    for (int mi = 0; mi < 4; ++mi) a[mi] = *(const s16x8*)&As[mi * 16 + ln][g * 8];
#pragma unroll
    for (int mi = 0; mi < 4; ++mi)
#pragma unroll
      for (int ni = 0; ni < 2; ++ni)
        acc[mi][ni] = __builtin_amdgcn_mfma_f32_16x16x32_bf16(a[mi], b[ni], acc[mi][ni], 0, 0, 0);
  }
#pragma unroll
  for (int mi = 0; mi < 4; ++mi) {
#pragma unroll
    for (int r = 0; r < 4; ++r) {
      int n = n0 + mi * 16 + g * 4 + r;
      if (n >= NN) continue;
      float di = dinv[n];
#pragma unroll
      for (int ni = 0; ni < 2; ++ni) {
        int c = w * 32 + ni * 16 + ln;
        xws8[(size_t)n * FD + c] = f2fp8(acc[mi][ni][r] * di);
      }
    }
  }
}

// ------- fused gather + DCRNN cell (32-row blocks, Ht phase-split) --------
// Gather: 8 thr/row x 16 feats (8 concurrent row streams per wave);
//   fp8 xws: ONE 16B load per row per thread; 2-edge int4 metadata loads.
//   acc fp32 in registers; agg = acc * dinv[n] -> bf16 As[:,0:128];
//   hs fp32 -> bf16 As[:,128:256].
// Phase 1: ZR GEMM (K=256) + Ht-top (K=128, agg half). z in registers.
// R epilogue: hsr = R*hs overwrites As hs-half.
// Phase 2: Ht-bottom (K=128). No barrier before Hn epilogue (disjoint cols).
// Hn epilogue: re-reads hs fp32 (L3-hot); relu(Hn) bf16 -> As[:,0:128].
// Classifier: waves 0,1 -> 16 rows each.

__global__ __launch_bounds__(256) void k_cell(
    const unsigned char* __restrict__ xws8, const float* __restrict__ dinv,
    const int* __restrict__ base, const int2* __restrict__ edge_s,
    const float* __restrict__ hs,
    const short* __restrict__ wtzr, const short* __restrict__ wth,
    const short* __restrict__ wtl, const float* __restrict__ bzp,
    const float* __restrict__ brp, const float* __restrict__ bhp,
    const float* __restrict__ bl, float* __restrict__ probs,
    float* __restrict__ Hn) {
  __shared__ __align__(16) short As[32][264];   // 16.9 KB
  const int tid = threadIdx.x;
  const int w = tid >> 6, l = tid & 63, g = l >> 4, ln = l & 15;
  const int n0 = blockIdx.x * 32;

  // ---- gather phase: row = tid>>3, 16 feats per thread ----
  {
    const int row = tid >> 3;
    const int c0 = (tid & 7) << 4;        // feature start (16 fp8 = 16 B)
    const int n = n0 + row;
    float acc[16];
    if (n < NN) {
      {
        int4 xv = *(const int4*)(xws8 + (size_t)n * FD + c0);
        fp8_set4(acc + 0, xv.x);
        fp8_set4(acc + 4, xv.y);
        fp8_set4(acc + 8, xv.z);
        fp8_set4(acc + 12, xv.w);
      }
      const int e0 = base[n], e1 = base[n + 1];
      int e = e0;
      if ((e & 1) && e < e1) {            // peel to 16B-align pair loads
        int2 ed = edge_s[e];
        float wv = __int_as_float(ed.y);
        int4 v = *(const int4*)(xws8 + (size_t)ed.x * FD + c0);
        fp8_fma4(acc + 0, v.x, wv);
        fp8_fma4(acc + 4, v.y, wv);
        fp8_fma4(acc + 8, v.z, wv);
        fp8_fma4(acc + 12, v.w, wv);
        ++e;
      }
      for (; e + 2 <= e1; e += 2) {
        int4 ep = *(const int4*)&edge_s[e];   // 2 edges, one 16B load
        float wa = __int_as_float(ep.y), wb = __int_as_float(ep.w);
        int4 va = *(const int4*)(xws8 + (size_t)ep.x * FD + c0);
        int4 vb = *(const int4*)(xws8 + (size_t)ep.z * FD + c0);
        fp8_fma4(acc + 0, va.x, wa);
        fp8_fma4(acc + 4, va.y, wa);
        fp8_fma4(acc + 8, va.z, wa);
        fp8_fma4(acc + 12, va.w, wa);
        fp8_fma4(acc + 0, vb.x, wb);
        fp8_fma4(acc + 4, vb.y, wb);
        fp8_fma4(acc + 8, vb.z, wb);
        fp8_fma4(acc + 12, vb.w, wb);
      }
      if (e < e1) {
        int2 ed = edge_s[e];
        float wv = __int_as_float(ed.y);
        int4 v = *(const int4*)(xws8 + (size_t)ed.x * FD + c0);
        fp8_fma4(acc + 0, v.x, wv);
        fp8_fma4(acc + 4, v.y, wv);
        fp8_fma4(acc + 8, v.z, wv);
        fp8_fma4(acc + 12, v.w, wv);
      }
      float d = dinv[n];
#pragma unroll
      for (int j = 0; j < 16; ++j) acc[j] *= d;
    } else {
#pragma unroll
      for (int j = 0; j < 16; ++j) acc[j] = 0.f;
    }
    s16x8 o0, o1;
#pragma unroll
    for (int j = 0; j < 8; ++j) {
      o0[j] = (short)f2bf(acc[j]);
      o1[j] = (short)f2bf(acc[8 + j]);
    }
    *(s16x8*)&As[row][c0] = o0;
    *(s16x8*)&As[row][c0 + 8] = o1;
    // stage hs half: same 16 cols at offset 128
    s16x8 h0 = {0,0,0,0,0,0,0,0}, h1 = {0,0,0,0,0,0,0,0};
    if (n < NN) {
      const float* hp = hs + (size_t)n * FD + c0;
      float4 f0 = *(const float4*)hp;
      float4 f1 = *(const float4*)(hp + 4);
      float4 f2 = *(const float4*)(hp + 8);
      float4 f3 = *(const float4*)(hp + 12);
      h0[0] = (short)f2bf(f0.x); h0[1] = (short)f2bf(f0.y);
      h0[2] = (short)f2bf(f0.z); h0[3] = (short)f2bf(f0.w);
      h0[4] = (short)f2bf(f1.x); h0[5] = (short)f2bf(f1.y);
      h0[6] = (short)f2bf(f1.z); h0[7] = (short)f2bf(f1.w);
      h1[0] = (short)f2bf(f2.x); h1[1] = (short)f2bf(f2.y);
      h1[2] = (short)f2bf(f2.z); h1[3] = (short)f2bf(f2.w);
      h1[4] = (short)f2bf(f3.x); h1[5] = (short)f2bf(f3.y);
      h1[6] = (short)f2bf(f3.z); h1[7] = (short)f2bf(f3.w);
    }
    *(s16x8*)&As[row][FD + c0] = h0;
    *(s16x8*)&As[row][FD + c0 + 8] = h1;
  }
  __syncthreads();

  f32x4 zacc[2][2];
  f32x4 acc2[2][2];   // Ht accumulator, fed in both phases
#pragma unroll
  for (int mi = 0; mi < 2; ++mi)
#pragma unroll
    for (int ni = 0; ni < 2; ++ni) acc2[mi][ni] = (f32x4){0.f, 0.f, 0.f, 0.f};

  // ---- phase 1: ZR (K=256) + Ht-top (K=128) ----
  {
    f32x4 acc[2][4];
#pragma unroll
    for (int mi = 0; mi < 2; ++mi)
#pragma unroll
      for (int ni = 0; ni < 4; ++ni) acc[mi][ni] = (f32x4){0.f, 0.f, 0.f, 0.f};
    const s16x8* wtz8 = (const s16x8*)wtzr;  // row = 256 shorts = 32 units
    const s16x8* wth8 = (const s16x8*)wth;
#pragma unroll 2
    for (int kci = 0; kci < 8; ++kci) {
      s16x8 b[4], a[2];
#pragma unroll
      for (int ni = 0; ni < 4; ++ni) {
        int col = (ni < 2) ? (w * 32 + ni * 16 + ln)
                           : (FD + w * 32 + (ni - 2) * 16 + ln);
        b[ni] = wtz8[(size_t)col * 32 + kci * 4 + g];
      }
#pragma unroll
      for (int mi = 0; mi < 2; ++mi)
        a[mi] = *(const s16x8*)&As[mi * 16 + ln][kci * 32 + g * 8];
#pragma unroll
      for (int mi = 0; mi < 2; ++mi)
#pragma unroll
        for (int ni = 0; ni < 4; ++ni)
          acc[mi][ni] = __builtin_amdgcn_mfma_f32_16x16x32_bf16(a[mi], b[ni], acc[mi][ni], 0, 0, 0);
      if (kci < 4) {  // Ht-top: same a fragments, agg half only
        s16x8 b2[2];
#pragma unroll
        for (int ni = 0; ni < 2; ++ni) {
          int col = w * 32 + ni * 16 + ln;
          b2[ni] = wth8[(size_t)col * 32 + kci * 4 + g];
        }
#pragma unroll
        for (int mi = 0; mi < 2; ++mi)
#pragma unroll
          for (int ni = 0; ni < 2; ++ni)
            acc2[mi][ni] = __builtin_amdgcn_mfma_f32_16x16x32_bf16(a[mi], b2[ni], acc2[mi][ni], 0, 0, 0);
      }
    }
    __syncthreads();  // all waves done reading As before hs-half overwrite

    // R epilogue: z -> registers; hsr = r*hs overwrites As[.][128+cc]
    float bz_c[2], br_c[2];
#pragma unroll
    for (int ni = 0; ni < 2; ++ni) {
      bz_c[ni] = bzp[w * 32 + ni * 16 + ln];
      br_c[ni] = brp[w * 32 + ni * 16 + ln];
    }
#pragma unroll
    for (int mi = 0; mi < 2; ++mi) {
#pragma unroll
      for (int r = 0; r < 4; ++r) {
        int row = mi * 16 + g * 4 + r;
#pragma unroll
        for (int ni = 0; ni < 2; ++ni) {
          zacc[mi][ni][r] = fast_sigmoid(acc[mi][ni][r] + bz_c[ni]);
          int cc = w * 32 + ni * 16 + ln;
          float rv = fast_sigmoid(acc[mi][ni + 2][r] + br_c[ni]);
          float hv = bf2f((unsigned short)As[row][FD + cc]);
          As[row][FD + cc] = (short)f2bf(rv * hv);
        }
      }
    }
  }
  __syncthreads();

  // ---- phase 2: Ht-bottom (hsr @ Wh[128:256], K=128) ----
  {
    const s16x8* wt8 = (const s16x8*)wth;
#pragma unroll 2
    for (int kci = 4; kci < 8; ++kci) {
      s16x8 b[2], a[2];
#pragma unroll
      for (int ni = 0; ni < 2; ++ni) {
        int col = w * 32 + ni * 16 + ln;
        b[ni] = wt8[(size_t)col * 32 + kci * 4 + g];
      }
#pragma unroll
      for (int mi = 0; mi < 2; ++mi)
        a[mi] = *(const s16x8*)&As[mi * 16 + ln][kci * 32 + g * 8];
#pragma unroll
      for (int mi = 0; mi < 2; ++mi)
#pragma unroll
        for (int ni = 0; ni < 2; ++ni)
          acc2[mi][ni] = __builtin_amdgcn_mfma_f32_16x16x32_bf16(a[mi], b[ni], acc2[mi][ni], 0, 0, 0);
    }
  }
  // NO barrier: phase 2 reads As cols 128-255; epilogue writes cols 0-127.

  // ---- Hn epilogue: hv re-read from global hs (L3-hot) ----
  {
    float bh_c[2];
#pragma unroll
    for (int ni = 0; ni < 2; ++ni) bh_c[ni] = bhp[w * 32 + ni * 16 + ln];
#pragma unroll
    for (int mi = 0; mi < 2; ++mi) {
#pragma unroll
      for (int r = 0; r < 4; ++r) {
        int row = mi * 16 + g * 4 + r;
        int n = n0 + row;
#pragma unroll
        for (int ni = 0; ni < 2; ++ni) {
          int c = w * 32 + ni * 16 + ln;
          float z = zacc[mi][ni][r];
          float ht = fast_tanh(acc2[mi][ni][r] + bh_c[ni]);
          if (n < NN) {
            float hv = hs[(size_t)n * FD + c];
            float hn = z * hv + (1.f - z) * ht;
            Hn[(size_t)n * FD + c] = hn;
            As[row][c] = (short)f2bf(fmaxf(hn, 0.f));
          } else {
            As[row][c] = 0;
          }
        }
      }
    }
  }
  __syncthreads();

  // ---- classifier: waves 0,1 -> rows [w*16, w*16+16); 16 classes ----
  if (w < 2) {
    f32x4 ac = (f32x4){0.f, 0.f, 0.f, 0.f};
    const s16x8* wtl8 = (const s16x8*)wtl;  // row = 128 shorts = 16 units
#pragma unroll
    for (int kci = 0; kci < 4; ++kci) {
      s16x8 a = *(const s16x8*)&As[w * 16 + ln][kci * 32 + g * 8];
      s16x8 bfr = wtl8[ln * 16 + kci * 4 + g];
      ac = __builtin_amdgcn_mfma_f32_16x16x32_bf16(a, bfr, ac, 0, 0, 0);
    }
    float blv = bl[ln];
#pragma unroll
    for (int r = 0; r < 4; ++r) {
      int n = n0 + w * 16 + g * 4 + r;
      float v = ac[r] + blv;
      float m = v;
#pragma unroll
      for (int msk = 1; msk < 16; msk <<= 1) m = fmaxf(m, __shfl_xor(m, msk, 64));
      float e = exp2f(1.44269504f * (v - m));
      float s = e;
#pragma unroll
      for (int msk = 1; msk < 16; msk <<= 1) s += __shfl_xor(s, msk, 64);
      if (n < NN) probs[(size_t)n * NCLS + ln] = e * __builtin_amdgcn_rcpf(s);
    }
  }
}

// ---------------- launch ----------------

extern "C" void kernel_launch(void* const* d_in, const int* in_sizes, int n_in,
                              void* d_out, int out_size, void* d_ws, size_t ws_size,
                              hipStream_t stream) {
  (void)in_sizes; (void)n_in; (void)out_size; (void)ws_size;
  const float* x   = (const float*)d_in[0];
  const int*   ei  = (const int*)d_in[1];
  const float* ew  = (const float*)d_in[2];
  const float* hs  = (const float*)d_in[3];
  const float* Wg  = (const float*)d_in[4];
  const float* bg  = (const float*)d_in[5];
  const float* Wz0 = (const float*)d_in[6];
  const float* Wz1 = (const float*)d_in[7];
  const float* bz  = (const float*)d_in[8];
  const float* Wr0 = (const float*)d_in[9];
  const float* Wr1 = (const float*)d_in[10];
  const float* br  = (const float*)d_in[11];
  const float* Wh0 = (const float*)d_in[12];
  const float* Wh1 = (const float*)d_in[13];
  const float* bh  = (const float*)d_in[14];
  const float* Wl  = (const float*)d_in[15];
  const float* bl  = (const float*)d_in[16];

  float* out   = (float*)d_out;
  float* probs = out;                      // [NN,16]
  float* Hn    = out + (size_t)NN * NCLS;  // [NN,128]

  float* w    = (float*)d_ws;
  float* dinv = w;                             // [NN]
  unsigned char* xws8 = (unsigned char*)(w + 50048);  // [NN*FD] fp8 (1.6M floats)
  // slack after xws8 (region reserved 2*NN*FD floats): parts + off16 live here
  unsigned long long* parts = (unsigned long long*)(w + 50048 + 1600000);  // [NCOPY*NN] u64 = 3.2M floats
  int*   off16 = (int*)(w + 50048 + 1600000 + 3200000);                    // [NCOPY*NN] int = 1.6M floats
  float* hsrf = w + 50048 + 2 * (size_t)NN * FD;         // CSR scratch region
  float* wsp  = hsrf + (size_t)NN * FD;        // tail: bf16 weights + biases

  short* wtzr = (short*)wsp;                       // 65536 shorts
  short* wth  = (short*)(wsp + 32768);             // 32768 shorts
  short* wtg  = (short*)(wsp + 32768 + 16384);     // 16384 shorts
  short* wtl  = (short*)(wsp + 32768 + 16384 + 8192);  // 2048 shorts
  float* bzp  = wsp + 32768 + 16384 + 8192 + 1024;
  float* brp  = bzp + 128;
  float* bhp  = brp + 128;

  // remaining CSR scratch in hsrf region:
  int2*  edge_s = (int2*)hsrf;                      // [NE] packed (src, ew)
  int*   basep = (int*)(hsrf + 2 * NE);             // [NN+1]
  int*   bsum  = (int*)(hsrf + 1650048);            // [SCAN_B]

  hipMemsetAsync(parts, 0, (size_t)NCOPY * NN * sizeof(unsigned long long),
                 stream);
  k_prep_hist<<<RB, 256, 0, stream>>>(Wz0, Wz1, Wr0, Wr1, Wh0, Wh1, Wg, Wl,
                                      bg, bz, br, bh, ei + NE, ew,
                                      wtzr, wth, wtg, wtl,
                                      bzp, brp, bhp, parts);
  k_reduce_scan1<<<SCAN_B, 256, 0, stream>>>(parts, dinv, basep, bsum);
  k_scan23<<<SCAN_B, 256, 0, stream>>>(basep, bsum, parts, off16);
  k_reorder_xw<<<RB + 782, 256, 0, stream>>>(ei, ew, off16, edge_s,
                                             x, wtg, dinv, xws8);
  k_cell<<<1563, 256, 0, stream>>>(xws8, dinv, basep, edge_s, hs,
                                   wtzr, wth, wtl, bzp, brp, bhp,
                                   bl, probs, Hn);
}

// Round 25
// 191.656 us; speedup vs baseline: 1.0471x; 1.0471x over previous
//
#include <hip/hip_runtime.h>
#include <math.h>

#define NN 50000
#define NE 800000
#define FD 128
#define CIN 256
#define NCLS 16
#define SCAN_B 196   // ceil(NN/256)
#define NCOPY 16
#define RB 1024      // reorder blocks (fixed: edge->copy map depends on it)
#define RSTRIDE (RB * 256)

typedef short s16x8 __attribute__((ext_vector_type(8)));
typedef float f32x4 __attribute__((ext_vector_type(4)));
typedef float f32x2 __attribute__((ext_vector_type(2)));

__device__ __forceinline__ unsigned short f2bf(float f) {
  union { float f; unsigned u; } v; v.f = f;
  unsigned r = v.u + 0x7fffu + ((v.u >> 16) & 1u);
  return (unsigned short)(r >> 16);
}

__device__ __forceinline__ float bf2f(unsigned short h) {
  union { unsigned u; float f; } v; v.u = ((unsigned)h) << 16;
  return v.f;
}

// fast transcendentals: v_exp_f32 computes 2^x; rcp is 1-instr approx
__device__ __forceinline__ float fast_sigmoid(float x) {
  return __builtin_amdgcn_rcpf(1.0f + exp2f(-1.44269504f * x));
}
__device__ __forceinline__ float fast_tanh(float x) {
  return 1.0f - 2.0f * __builtin_amdgcn_rcpf(1.0f + exp2f(2.88539008f * x));
}

// fp8 (OCP e4m3) helpers: HW single-instruction converts on gfx950
__device__ __forceinline__ unsigned char f2fp8(float v) {
  int pk = __builtin_amdgcn_cvt_pk_fp8_f32(v, 0.f, 0, false);
  return (unsigned char)(pk & 0xff);
}
__device__ __forceinline__ void fp8_set4(float* a, int v) {
  f32x2 lo = __builtin_amdgcn_cvt_pk_f32_fp8(v, false);
  f32x2 hi = __builtin_amdgcn_cvt_pk_f32_fp8(v, true);
  a[0] = lo.x; a[1] = lo.y; a[2] = hi.x; a[3] = hi.y;
}
__device__ __forceinline__ void fp8_fma4(float* a, int v, float wv) {
  f32x2 lo = __builtin_amdgcn_cvt_pk_f32_fp8(v, false);
  f32x2 hi = __builtin_amdgcn_cvt_pk_f32_fp8(v, true);
  a[0] = fmaf(wv, lo.x, a[0]); a[1] = fmaf(wv, lo.y, a[1]);
  a[2] = fmaf(wv, hi.x, a[2]); a[3] = fmaf(wv, hi.y, a[3]);
}

// -- fused prep + histogram: weight transpose/bias fold hides under atomics --
// parts must be pre-zeroed (hipMemsetAsync). Edge->copy mapping (c =
// blockIdx&15, grid-stride RSTRIDE) MUST match k_reorder_xw's reorder path.

__global__ void k_prep_hist(
    const float* __restrict__ Wz0, const float* __restrict__ Wz1,
    const float* __restrict__ Wr0, const float* __restrict__ Wr1,
    const float* __restrict__ Wh0, const float* __restrict__ Wh1,
    const float* __restrict__ Wg, const float* __restrict__ Wl,
    const float* __restrict__ bg, const float* __restrict__ bz,
    const float* __restrict__ br, const float* __restrict__ bh,
    const int* __restrict__ dst, const float* __restrict__ ew,
    short* __restrict__ wtzr, short* __restrict__ wth,
    short* __restrict__ wtg, short* __restrict__ wtl,
    float* __restrict__ bzp, float* __restrict__ brp,
    float* __restrict__ bhp, unsigned long long* __restrict__ parts) {
  int i = blockIdx.x * blockDim.x + threadIdx.x;
  if (i < 65536) {
    int n = i >> 8, k = i & 255;
    float v = (n < 128) ? (Wz0[k * 128 + n] + Wz1[k * 128 + n])
                        : (Wr0[k * 128 + (n - 128)] + Wr1[k * 128 + (n - 128)]);
    wtzr[i] = (short)f2bf(v);
  } else if (i < 98304) {
    int j = i - 65536; int n = j >> 8, k = j & 255;
    wth[j] = (short)f2bf(Wh0[k * 128 + n] + Wh1[k * 128 + n]);
  } else if (i < 114688) {
    int j = i - 98304; int n = j >> 7, k = j & 127;
    wtg[j] = (short)f2bf(Wg[k * 128 + n]);
  } else if (i < 116736) {
    int j = i - 114688; int n = j >> 7, k = j & 127;
    wtl[j] = (short)f2bf(Wl[k * 16 + n]);
  } else if (i < 116864) {
    int c = i - 116736;
    float sz = bz[c], sr = br[c], sh = bh[c];
    for (int k = 0; k < 128; ++k) {
      float gv = bg[k];
      sz += gv * (Wz0[k * 128 + c] + Wz1[k * 128 + c]);
      sr += gv * (Wr0[k * 128 + c] + Wr1[k * 128 + c]);
      sh += gv * (Wh0[k * 128 + c] + Wh1[k * 128 + c]);
    }
    bzp[c] = sz; brp[c] = sr; bhp[c] = sh;
  }
  // histogram (all threads)
  const int c = blockIdx.x & (NCOPY - 1);
  unsigned long long* __restrict__ p = parts + (size_t)c * NN;
  for (int e = i; e < NE; e += RSTRIDE) {
    int d = dst[e];
    unsigned long long pk = (1ULL << 40) +
        (unsigned long long)(ew[e] * 4294967296.0f + 0.5f);
    atomicAdd(&p[d], pk);
  }
}

// fused: fold copies -> dinv ; block-local exclusive scan of counts
__global__ __launch_bounds__(256) void k_reduce_scan1(
    const unsigned long long* __restrict__ parts, float* __restrict__ dinv,
    int* __restrict__ base, int* __restrict__ bsum) {
  __shared__ int ts[256];
  const int t = threadIdx.x, b = blockIdx.x;
  const int i = b * 256 + t;
  int ct = 0;
  if (i < NN) {
    double frac = 0.0;
#pragma unroll
    for (int c = 0; c < NCOPY; ++c) {
      unsigned long long v = parts[(size_t)c * NN + i];
      ct += (int)(v >> 40);
      frac += (double)(v & 0xFFFFFFFFFFULL);
    }
    double deg = 1.0 + frac * (1.0 / 4294967296.0);
    dinv[i] = rsqrtf((float)deg);
  }
  ts[t] = ct;
  __syncthreads();
#pragma unroll
  for (int off = 1; off < 256; off <<= 1) {
    int u = (t >= off) ? ts[t - off] : 0;
    __syncthreads();
    ts[t] += u;
    __syncthreads();
  }
  if (i < NN) base[i] = ts[t] - ct;
  if (t == 255) bsum[b] = ts[255];
}

// scan2 folded in: every block redundantly scans bsum[196] in LDS,
// picks its own offset, finalizes base and carves per-copy cursors.
__global__ __launch_bounds__(256) void k_scan23(
    int* __restrict__ base, const int* __restrict__ bsum,
    const unsigned long long* __restrict__ parts, int* __restrict__ off16) {
  __shared__ int ts[256];
  __shared__ int bo;
  const int t = threadIdx.x;
  int v = (t < SCAN_B) ? bsum[t] : 0;
  ts[t] = v;
  __syncthreads();
#pragma unroll
  for (int off = 1; off < 256; off <<= 1) {
    int u = (t >= off) ? ts[t - off] : 0;
    __syncthreads();
    ts[t] += u;
    __syncthreads();
  }
  if (t == blockIdx.x) bo = ts[t] - v;          // boff[blockIdx]
  if (blockIdx.x == 0 && t == 255) base[NN] = ts[255];
  __syncthreads();
  const int boff = bo;
  const int i = blockIdx.x * 256 + t;
  if (i >= NN) return;
  int b = base[i] + boff;
  base[i] = b;
  int run = b;
#pragma unroll
  for (int c = 0; c < NCOPY; ++c) {
    off16[(size_t)c * NN + i] = run;
    run += (int)(parts[(size_t)c * NN + i] >> 40);
  }
}

// ---- heterogeneous fused kernel: reorder (blocks 0..RB-1)  ||  xw GEMM ----
// Reorder path: stride RSTRIDE, c = blockIdx&15 — MUST match k_prep_hist.
// xw path: blocks RB.. compute xws8 = fp8(dinv[n] * (x @ Wg)) via MFMA.

__global__ __launch_bounds__(256) void k_reorder_xw(
    const int* __restrict__ ei, const float* __restrict__ ew,
    int* __restrict__ off16, int2* __restrict__ edge_s,
    const float* __restrict__ x, const short* __restrict__ wtg,
    const float* __restrict__ dinv, unsigned char* __restrict__ xws8) {
  if (blockIdx.x < RB) {
    // ---------------- reorder path ----------------
    const int c = blockIdx.x & (NCOPY - 1);
    int* __restrict__ cur = off16 + (size_t)c * NN;
    int i = blockIdx.x * 256 + threadIdx.x;
    const int* __restrict__ src = ei;
    const int* __restrict__ dst = ei + NE;
    for (int e = i; e < NE; e += RSTRIDE) {
      int s = src[e], d = dst[e];
      int pos = atomicAdd(&cur[d], 1);
      edge_s[pos] = make_int2(s, __float_as_int(ew[e]));
    }
    return;
  }
  // ---------------- xw MFMA path ----------------
  __shared__ __align__(16) short As[64][40];
  const int tid = threadIdx.x;
  const int w = tid >> 6, l = tid & 63, g = l >> 4, ln = l & 15;
  const int n0 = (blockIdx.x - RB) * 64;
  const int srow = tid >> 2, sk0 = (tid & 3) << 3;
  const s16x8* wt8 = (const s16x8*)wtg;

  f32x4 acc[4][2];
#pragma unroll
  for (int mi = 0; mi < 4; ++mi)
#pragma unroll
    for (int ni = 0; ni < 2; ++ni) acc[mi][ni] = (f32x4){0.f, 0.f, 0.f, 0.f};

  for (int kci = 0; kci < 4; ++kci) {
    int kg = kci * 32 + sk0;
    int n = n0 + srow;
    s16x8 av = {0, 0, 0, 0, 0, 0, 0, 0};
    if (n < NN) {
      const float* src = x + (size_t)n * FD + kg;
      float4 f0 = *(const float4*)src;
      float4 f1 = *(const float4*)(src + 4);
      av[0] = (short)f2bf(f0.x); av[1] = (short)f2bf(f0.y);
      av[2] = (short)f2bf(f0.z); av[3] = (short)f2bf(f0.w);
      av[4] = (short)f2bf(f1.x); av[5] = (short)f2bf(f1.y);
      av[6] = (short)f2bf(f1.z); av[7] = (short)f2bf(f1.w);
    }
    __syncthreads();
    *(s16x8*)&As[srow][sk0] = av;
    __syncthreads();
    s16x8 b[2], a[4];
#pragma unroll
    for (int ni = 0; ni < 2; ++ni) {
      int col = w * 32 + ni * 16 + ln;
      b[ni] = wt8[(size_t)col * 16 + kci * 4 + g];
    }
#pragma unroll
    for (int mi = 0; mi < 4; ++mi) a[mi] = *(const s16x8*)&As[mi * 16 + ln][g * 8];
#pragma unroll
    for (int mi = 0; mi < 4; ++mi)
#pragma unroll
      for (int ni = 0; ni < 2; ++ni)
        acc[mi][ni] = __builtin_amdgcn_mfma_f32_16x16x32_bf16(a[mi], b[ni], acc[mi][ni], 0, 0, 0);
  }
#pragma unroll
  for (int mi = 0; mi < 4; ++mi) {
#pragma unroll
    for (int r = 0; r < 4; ++r) {
      int n = n0 + mi * 16 + g * 4 + r;
      if (n >= NN) continue;
      float di = dinv[n];
#pragma unroll
      for (int ni = 0; ni < 2; ++ni) {
        int c = w * 32 + ni * 16 + ln;
        xws8[(size_t)n * FD + c] = f2fp8(acc[mi][ni][r] * di);
      }
    }
  }
}

// ------- fused gather + DCRNN cell (32-row blocks, Ht phase-split) --------
// Gather: 8 thr/row x 16 feats (8 concurrent row streams per wave);
//   fp8 xws: ONE 16B load per row per thread; 2-edge int4 metadata loads.
//   acc fp32 in registers; agg = acc * dinv[n] -> bf16 As[:,0:128];
//   hs fp32 -> bf16 As[:,128:256].
// Phase 1: ZR GEMM (K=256) + Ht-top (K=128, agg half). z in registers.
// R epilogue: hsr = R*hs overwrites As hs-half.
// Phase 2: Ht-bottom (K=128). No barrier before Hn epilogue (disjoint cols).
// Hn epilogue: re-reads hs fp32 (L3-hot); relu(Hn) bf16 -> As[:,0:128].
// Classifier: waves 0,1 -> 16 rows each.

__global__ __launch_bounds__(256) void k_cell(
    const unsigned char* __restrict__ xws8, const float* __restrict__ dinv,
    const int* __restrict__ base, const int2* __restrict__ edge_s,
    const float* __restrict__ hs,
    const short* __restrict__ wtzr, const short* __restrict__ wth,
    const short* __restrict__ wtl, const float* __restrict__ bzp,
    const float* __restrict__ brp, const float* __restrict__ bhp,
    const float* __restrict__ bl, float* __restrict__ probs,
    float* __restrict__ Hn) {
  __shared__ __align__(16) short As[32][264];   // 16.9 KB
  const int tid = threadIdx.x;
  const int w = tid >> 6, l = tid & 63, g = l >> 4, ln = l & 15;
  const int n0 = blockIdx.x * 32;

  // ---- gather phase: row = tid>>3, 16 feats per thread ----
  {
    const int row = tid >> 3;
    const int c0 = (tid & 7) << 4;        // feature start (16 fp8 = 16 B)
    const int n = n0 + row;
    float acc[16];
    if (n < NN) {
      {
        int4 xv = *(const int4*)(xws8 + (size_t)n * FD + c0);
        fp8_set4(acc + 0, xv.x);
        fp8_set4(acc + 4, xv.y);
        fp8_set4(acc + 8, xv.z);
        fp8_set4(acc + 12, xv.w);
      }
      const int e0 = base[n], e1 = base[n + 1];
      int e = e0;
      if ((e & 1) && e < e1) {            // peel to 16B-align pair loads
        int2 ed = edge_s[e];
        float wv = __int_as_float(ed.y);
        int4 v = *(const int4*)(xws8 + (size_t)ed.x * FD + c0);
        fp8_fma4(acc + 0, v.x, wv);
        fp8_fma4(acc + 4, v.y, wv);
        fp8_fma4(acc + 8, v.z, wv);
        fp8_fma4(acc + 12, v.w, wv);
        ++e;
      }
      for (; e + 2 <= e1; e += 2) {
        int4 ep = *(const int4*)&edge_s[e];   // 2 edges, one 16B load
        float wa = __int_as_float(ep.y), wb = __int_as_float(ep.w);
        int4 va = *(const int4*)(xws8 + (size_t)ep.x * FD + c0);
        int4 vb = *(const int4*)(xws8 + (size_t)ep.z * FD + c0);
        fp8_fma4(acc + 0, va.x, wa);
        fp8_fma4(acc + 4, va.y, wa);
        fp8_fma4(acc + 8, va.z, wa);
        fp8_fma4(acc + 12, va.w, wa);
        fp8_fma4(acc + 0, vb.x, wb);
        fp8_fma4(acc + 4, vb.y, wb);
        fp8_fma4(acc + 8, vb.z, wb);
        fp8_fma4(acc + 12, vb.w, wb);
      }
      if (e < e1) {
        int2 ed = edge_s[e];
        float wv = __int_as_float(ed.y);
        int4 v = *(const int4*)(xws8 + (size_t)ed.x * FD + c0);
        fp8_fma4(acc + 0, v.x, wv);
        fp8_fma4(acc + 4, v.y, wv);
        fp8_fma4(acc + 8, v.z, wv);
        fp8_fma4(acc + 12, v.w, wv);
      }
      float d = dinv[n];
#pragma unroll
      for (int j = 0; j < 16; ++j) acc[j] *= d;
    } else {
#pragma unroll
      for (int j = 0; j < 16; ++j) acc[j] = 0.f;
    }
    s16x8 o0, o1;
#pragma unroll
    for (int j = 0; j < 8; ++j) {
      o0[j] = (short)f2bf(acc[j]);
      o1[j] = (short)f2bf(acc[8 + j]);
    }
    *(s16x8*)&As[row][c0] = o0;
    *(s16x8*)&As[row][c0 + 8] = o1;
    // stage hs half: same 16 cols at offset 128
    s16x8 h0 = {0,0,0,0,0,0,0,0}, h1 = {0,0,0,0,0,0,0,0};
    if (n < NN) {
      const float* hp = hs + (size_t)n * FD + c0;
      float4 f0 = *(const float4*)hp;
      float4 f1 = *(const float4*)(hp + 4);
      float4 f2 = *(const float4*)(hp + 8);
      float4 f3 = *(const float4*)(hp + 12);
      h0[0] = (short)f2bf(f0.x); h0[1] = (short)f2bf(f0.y);
      h0[2] = (short)f2bf(f0.z); h0[3] = (short)f2bf(f0.w);
      h0[4] = (short)f2bf(f1.x); h0[5] = (short)f2bf(f1.y);
      h0[6] = (short)f2bf(f1.z); h0[7] = (short)f2bf(f1.w);
      h1[0] = (short)f2bf(f2.x); h1[1] = (short)f2bf(f2.y);
      h1[2] = (short)f2bf(f2.z); h1[3] = (short)f2bf(f2.w);
      h1[4] = (short)f2bf(f3.x); h1[5] = (short)f2bf(f3.y);
      h1[6] = (short)f2bf(f3.z); h1[7] = (short)f2bf(f3.w);
    }
    *(s16x8*)&As[row][FD + c0] = h0;
    *(s16x8*)&As[row][FD + c0 + 8] = h1;
  }
  __syncthreads();

  f32x4 zacc[2][2];
  f32x4 acc2[2][2];   // Ht accumulator, fed in both phases
#pragma unroll
  for (int mi = 0; mi < 2; ++mi)
#pragma unroll
    for (int ni = 0; ni < 2; ++ni) acc2[mi][ni] = (f32x4){0.f, 0.f, 0.f, 0.f};

  // ---- phase 1: ZR (K=256) + Ht-top (K=128) ----
  {
    f32x4 acc[2][4];
#pragma unroll
    for (int mi = 0; mi < 2; ++mi)
#pragma unroll
      for (int ni = 0; ni < 4; ++ni) acc[mi][ni] = (f32x4){0.f, 0.f, 0.f, 0.f};
    const s16x8* wtz8 = (const s16x8*)wtzr;  // row = 256 shorts = 32 units
    const s16x8* wth8 = (const s16x8*)wth;
#pragma unroll 2
    for (int kci = 0; kci < 8; ++kci) {
      s16x8 b[4], a[2];
#pragma unroll
      for (int ni = 0; ni < 4; ++ni) {
        int col = (ni < 2) ? (w * 32 + ni * 16 + ln)
                           : (FD + w * 32 + (ni - 2) * 16 + ln);
        b[ni] = wtz8[(size_t)col * 32 + kci * 4 + g];
      }
#pragma unroll
      for (int mi = 0; mi < 2; ++mi)
        a[mi] = *(const s16x8*)&As[mi * 16 + ln][kci * 32 + g * 8];
#pragma unroll
      for (int mi = 0; mi < 2; ++mi)
#pragma unroll
        for (int ni = 0; ni < 4; ++ni)
          acc[mi][ni] = __builtin_amdgcn_mfma_f32_16x16x32_bf16(a[mi], b[ni], acc[mi][ni], 0, 0, 0);
      if (kci < 4) {  // Ht-top: same a fragments, agg half only
        s16x8 b2[2];
#pragma unroll
        for (int ni = 0; ni < 2; ++ni) {
          int col = w * 32 + ni * 16 + ln;
          b2[ni] = wth8[(size_t)col * 32 + kci * 4 + g];
        }
#pragma unroll
        for (int mi = 0; mi < 2; ++mi)
#pragma unroll
          for (int ni = 0; ni < 2; ++ni)
            acc2[mi][ni] = __builtin_amdgcn_mfma_f32_16x16x32_bf16(a[mi], b2[ni], acc2[mi][ni], 0, 0, 0);
      }
    }
    __syncthreads();  // all waves done reading As before hs-half overwrite

    // R epilogue: z -> registers; hsr = r*hs overwrites As[.][128+cc]
    float bz_c[2], br_c[2];
#pragma unroll
    for (int ni = 0; ni < 2; ++ni) {
      bz_c[ni] = bzp[w * 32 + ni * 16 + ln];
      br_c[ni] = brp[w * 32 + ni * 16 + ln];
    }
#pragma unroll
    for (int mi = 0; mi < 2; ++mi) {
#pragma unroll
      for (int r = 0; r < 4; ++r) {
        int row = mi * 16 + g * 4 + r;
#pragma unroll
        for (int ni = 0; ni < 2; ++ni) {
          zacc[mi][ni][r] = fast_sigmoid(acc[mi][ni][r] + bz_c[ni]);
          int cc = w * 32 + ni * 16 + ln;
          float rv = fast_sigmoid(acc[mi][ni + 2][r] + br_c[ni]);
          float hv = bf2f((unsigned short)As[row][FD + cc]);
          As[row][FD + cc] = (short)f2bf(rv * hv);
        }
      }
    }
  }
  __syncthreads();

  // ---- phase 2: Ht-bottom (hsr @ Wh[128:256], K=128) ----
  {
    const s16x8* wt8 = (const s16x8*)wth;
#pragma unroll 2
    for (int kci = 4; kci < 8; ++kci) {
      s16x8 b[2], a[2];
#pragma unroll
      for (int ni = 0; ni < 2; ++ni) {
        int col = w * 32 + ni * 16 + ln;
        b[ni] = wt8[(size_t)col * 32 + kci * 4 + g];
      }
#pragma unroll
      for (int mi = 0; mi < 2; ++mi)
        a[mi] = *(const s16x8*)&As[mi * 16 + ln][kci * 32 + g * 8];
#pragma unroll
      for (int mi = 0; mi < 2; ++mi)
#pragma unroll
        for (int ni = 0; ni < 2; ++ni)
          acc2[mi][ni] = __builtin_amdgcn_mfma_f32_16x16x32_bf16(a[mi], b[ni], acc2[mi][ni], 0, 0, 0);
    }
  }
  // NO barrier: phase 2 reads As cols 128-255; epilogue writes cols 0-127.

  // ---- Hn epilogue: hv re-read from global hs (L3-hot) ----
  {
    float bh_c[2];
#pragma unroll
    for (int ni = 0; ni < 2; ++ni) bh_c[ni] = bhp[w * 32 + ni * 16 + ln];
#pragma unroll
    for (int mi = 0; mi < 2; ++mi) {
#pragma unroll
      for (int r = 0; r < 4; ++r) {
        int row = mi * 16 + g * 4 + r;
        int n = n0 + row;
#pragma unroll
        for (int ni = 0; ni < 2; ++ni) {
          int c = w * 32 + ni * 16 + ln;
          float z = zacc[mi][ni][r];
          float ht = fast_tanh(acc2[mi][ni][r] + bh_c[ni]);
          if (n < NN) {
            float hv = hs[(size_t)n * FD + c];
            float hn = z * hv + (1.f - z) * ht;
            Hn[(size_t)n * FD + c] = hn;
            As[row][c] = (short)f2bf(fmaxf(hn, 0.f));
          } else {
            As[row][c] = 0;
          }
        }
      }
    }
  }
  __syncthreads();

  // ---- classifier: waves 0,1 -> rows [w*16, w*16+16); 16 classes ----
  if (w < 2) {
    f32x4 ac = (f32x4){0.f, 0.f, 0.f, 0.f};
    const s16x8* wtl8 = (const s16x8*)wtl;  // row = 128 shorts = 16 units
#pragma unroll
    for (int kci = 0; kci < 4; ++kci) {
      s16x8 a = *(const s16x8*)&As[w * 16 + ln][kci * 32 + g * 8];
      s16x8 bfr = wtl8[ln * 16 + kci * 4 + g];
      ac = __builtin_amdgcn_mfma_f32_16x16x32_bf16(a, bfr, ac, 0, 0, 0);
    }
    float blv = bl[ln];
#pragma unroll
    for (int r = 0; r < 4; ++r) {
      int n = n0 + w * 16 + g * 4 + r;
      float v = ac[r] + blv;
      float m = v;
#pragma unroll
      for (int msk = 1; msk < 16; msk <<= 1) m = fmaxf(m, __shfl_xor(m, msk, 64));
      float e = exp2f(1.44269504f * (v - m));
      float s = e;
#pragma unroll
      for (int msk = 1; msk < 16; msk <<= 1) s += __shfl_xor(s, msk, 64);
      if (n < NN) probs[(size_t)n * NCLS + ln] = e * __builtin_amdgcn_rcpf(s);
    }
  }
}

// ---------------- launch ----------------

extern "C" void kernel_launch(void* const* d_in, const int* in_sizes, int n_in,
                              void* d_out, int out_size, void* d_ws, size_t ws_size,
                              hipStream_t stream) {
  (void)in_sizes; (void)n_in; (void)out_size; (void)ws_size;
  const float* x   = (const float*)d_in[0];
  const int*   ei  = (const int*)d_in[1];
  const float* ew  = (const float*)d_in[2];
  const float* hs  = (const float*)d_in[3];
  const float* Wg  = (const float*)d_in[4];
  const float* bg  = (const float*)d_in[5];
  const float* Wz0 = (const float*)d_in[6];
  const float* Wz1 = (const float*)d_in[7];
  const float* bz  = (const float*)d_in[8];
  const float* Wr0 = (const float*)d_in[9];
  const float* Wr1 = (const float*)d_in[10];
  const float* br  = (const float*)d_in[11];
  const float* Wh0 = (const float*)d_in[12];
  const float* Wh1 = (const float*)d_in[13];
  const float* bh  = (const float*)d_in[14];
  const float* Wl  = (const float*)d_in[15];
  const float* bl  = (const float*)d_in[16];

  float* out   = (float*)d_out;
  float* probs = out;                      // [NN,16]
  float* Hn    = out + (size_t)NN * NCLS;  // [NN,128]

  float* w    = (float*)d_ws;
  float* dinv = w;                             // [NN]
  unsigned char* xws8 = (unsigned char*)(w + 50048);  // [NN*FD] fp8 e4m3
  float* hsrf = w + 50048 + 2 * (size_t)NN * FD;         // CSR scratch region
  float* wsp  = hsrf + (size_t)NN * FD;        // tail: bf16 weights + biases

  short* wtzr = (short*)wsp;                       // 65536 shorts
  short* wth  = (short*)(wsp + 32768);             // 32768 shorts
  short* wtg  = (short*)(wsp + 32768 + 16384);     // 16384 shorts
  short* wtl  = (short*)(wsp + 32768 + 16384 + 8192);  // 2048 shorts
  float* bzp  = wsp + 32768 + 16384 + 8192 + 1024;
  float* brp  = bzp + 128;
  float* bhp  = brp + 128;

  // CSR scratch laid out in hsrf region (6.4M floats available):
  int2*  edge_s = (int2*)hsrf;                      // [NE] packed (src, ew)
  int*   basep = (int*)(hsrf + 2 * NE);             // [NN+1]
  int*   bsum  = (int*)(hsrf + 1650048);            // [SCAN_B]
  unsigned long long* parts = (unsigned long long*)(hsrf + 1651024);  // [NCOPY*NN]
  int*   off16 = (int*)(hsrf + 3301040);            // [NCOPY*NN]

  hipMemsetAsync(parts, 0, (size_t)NCOPY * NN * sizeof(unsigned long long),
                 stream);
  k_prep_hist<<<RB, 256, 0, stream>>>(Wz0, Wz1, Wr0, Wr1, Wh0, Wh1, Wg, Wl,
                                      bg, bz, br, bh, ei + NE, ew,
                                      wtzr, wth, wtg, wtl,
                                      bzp, brp, bhp, parts);
  k_reduce_scan1<<<SCAN_B, 256, 0, stream>>>(parts, dinv, basep, bsum);
  k_scan23<<<SCAN_B, 256, 0, stream>>>(basep, bsum, parts, off16);
  k_reorder_xw<<<RB + 782, 256, 0, stream>>>(ei, ew, off16, edge_s,
                                             x, wtg, dinv, xws8);
  k_cell<<<1563, 256, 0, stream>>>(xws8, dinv, basep, edge_s, hs,
                                   wtzr, wth, wtl, bzp, brp, bhp,
                                   bl, probs, Hn);
}